// Round 4
// baseline (320.171 us; speedup 1.0000x reference)
//
#include <hip/hip_runtime.h>
#include <hip/hip_fp16.h>

// Clang-native vector types (__builtin_nontemporal_load rejects HIP_vector_type).
typedef float    vfloat4 __attribute__((ext_vector_type(4)));
typedef int      vint4   __attribute__((ext_vector_type(4)));
typedef _Float16 vhalf4  __attribute__((ext_vector_type(4)));

// Phase 1 (fused): values_h = fp16(pred*(ub-lb)+lb); zero ax; zero out.
// fp16 table is 2 MB (vs 4 MB fp32) -> fits in half an XCD L2, halves
// gather line-fill traffic.
__global__ void denorm_zero_kernel(const vfloat4* __restrict__ pred,
                                   const vfloat4* __restrict__ lb,
                                   const vfloat4* __restrict__ ub,
                                   vhalf4* __restrict__ values_h,
                                   vfloat4* __restrict__ ax,
                                   float* __restrict__ out,
                                   int n4v, int n4c) {
    int i = blockIdx.x * blockDim.x + threadIdx.x;
    if (i < n4v) {
        vfloat4 p = pred[i], l = lb[i], u = ub[i];
        vhalf4 h;
        h.x = (_Float16)fmaf(p.x, u.x - l.x, l.x);
        h.y = (_Float16)fmaf(p.y, u.y - l.y, l.y);
        h.z = (_Float16)fmaf(p.z, u.z - l.z, l.z);
        h.w = (_Float16)fmaf(p.w, u.w - l.w, l.w);
        values_h[i] = h;
    }
    if (i < n4c) {
        vfloat4 z = {0.f, 0.f, 0.f, 0.f};
        ax[i] = z;
    }
    if (i == 0) *out = 0.0f;
}

// Phase 2: thread-coarsened segmented sum (K=16 nnz/thread, coalesced x4
// loads). Each block covers exactly 4096 sorted nnz ~= 260 consecutive rows:
// partials go into an LDS window (fast ds_add_f32), then ONE coalesced
// writeback per block: plain stores for interior rows (exclusively owned),
// global atomicAdd only for the two boundary rows. This kills the 2M global
// atomics and the 8x dirty-line write amplification seen in rocprof.
#define WIN 4096

__global__ void scatter_kernel(const vfloat4* __restrict__ coeff,
                               const vint4* __restrict__ cidx,
                               const vint4* __restrict__ vidx,
                               const _Float16* __restrict__ values,
                               float* __restrict__ ax,
                               int nnz) {
    __shared__ float lwin[WIN];
    __shared__ int srow[2];
    const int K = 16;
    const int tib = threadIdx.x;

    long blockbase = (long)blockIdx.x * 256 * K;
    if (blockbase >= nnz) return;  // uniform per block

    for (int o = tib; o < WIN; o += 256) lwin[o] = 0.0f;
    if (tib == 0) {
        const int* ci = (const int*)cidx;
        srow[0] = ci[blockbase];
        long lastl = blockbase + 256L * K;
        if (lastl > nnz) lastl = nnz;
        srow[1] = ci[lastl - 1];
    }
    __syncthreads();
    const int rlo = srow[0];
    const int rhi = srow[1];

    long base = blockbase + (long)tib * K;
    if (base < nnz) {
        if (base + K <= nnz) {
            long b4 = base / 4;
            int cseg[16]; int vix[16]; float cf[16];
            #pragma unroll
            for (int j = 0; j < 4; j++) {
                vint4 c = __builtin_nontemporal_load(&cidx[b4 + j]);
                cseg[4*j+0] = c.x; cseg[4*j+1] = c.y; cseg[4*j+2] = c.z; cseg[4*j+3] = c.w;
            }
            #pragma unroll
            for (int j = 0; j < 4; j++) {
                vint4 v = __builtin_nontemporal_load(&vidx[b4 + j]);
                vix[4*j+0] = v.x; vix[4*j+1] = v.y; vix[4*j+2] = v.z; vix[4*j+3] = v.w;
            }
            float vals[16];
            #pragma unroll
            for (int k = 0; k < 16; k++) vals[k] = (float)values[vix[k]];
            #pragma unroll
            for (int j = 0; j < 4; j++) {
                vfloat4 f = __builtin_nontemporal_load(&coeff[b4 + j]);
                cf[4*j+0] = f.x; cf[4*j+1] = f.y; cf[4*j+2] = f.z; cf[4*j+3] = f.w;
            }

            int cur = cseg[0];
            float acc = cf[0] * vals[0];
            #pragma unroll
            for (int k = 1; k < 16; k++) {
                if (cseg[k] == cur) {
                    acc = fmaf(cf[k], vals[k], acc);
                } else {
                    unsigned off = (unsigned)(cur - rlo);
                    if (off < (unsigned)WIN) atomicAdd(&lwin[off], acc);
                    else atomicAdd(&ax[cur], acc);
                    cur = cseg[k];
                    acc = cf[k] * vals[k];
                }
            }
            unsigned off = (unsigned)(cur - rlo);
            if (off < (unsigned)WIN) atomicAdd(&lwin[off], acc);
            else atomicAdd(&ax[cur], acc);
        } else {
            // Tail chunk: scalar.
            const int* ci = (const int*)cidx;
            const int* vi = (const int*)vidx;
            const float* cf = (const float*)coeff;
            int cur = ci[base];
            float acc = cf[base] * (float)values[vi[base]];
            for (long k = base + 1; k < nnz; k++) {
                int s = ci[k];
                float p = cf[k] * (float)values[vi[k]];
                if (s == cur) acc += p;
                else {
                    unsigned off = (unsigned)(cur - rlo);
                    if (off < (unsigned)WIN) atomicAdd(&lwin[off], acc);
                    else atomicAdd(&ax[cur], acc);
                    cur = s; acc = p;
                }
            }
            unsigned off = (unsigned)(cur - rlo);
            if (off < (unsigned)WIN) atomicAdd(&lwin[off], acc);
            else atomicAdd(&ax[cur], acc);
        }
    }
    __syncthreads();

    // Coalesced writeback of the block's row range.
    int span = rhi - rlo + 1;
    int wl = span < WIN ? span : WIN;
    for (int o = tib; o < wl; o += 256) {
        int r = rlo + o;
        float v = lwin[o];
        if (r == rlo || r == rhi) atomicAdd(&ax[r], v);  // shared with neighbor blocks
        else ax[r] = v;                                   // exclusively owned
    }
}

// Phase 3: violations by sense (x4 vectorized), block reduce, one atomic.
__global__ void violation_kernel(const vfloat4* __restrict__ ax,
                                 const vfloat4* __restrict__ rhs,
                                 const vint4* __restrict__ sense,
                                 float* __restrict__ out,
                                 int n4, float inv_n) {
    __shared__ float warp_sums[4];
    int i = blockIdx.x * blockDim.x + threadIdx.x;

    float viol = 0.0f;
    if (i < n4) {
        vfloat4 a = ax[i], r = rhs[i];
        vint4 s = sense[i];
        float d, pos, neg;
        d = a.x - r.x; pos = fmaxf(d, 0.f); neg = fmaxf(-d, 0.f);
        viol += (s.x == 1) ? pos : (s.x == 2) ? neg : (s.x == 3) ? (pos + neg) : 0.f;
        d = a.y - r.y; pos = fmaxf(d, 0.f); neg = fmaxf(-d, 0.f);
        viol += (s.y == 1) ? pos : (s.y == 2) ? neg : (s.y == 3) ? (pos + neg) : 0.f;
        d = a.z - r.z; pos = fmaxf(d, 0.f); neg = fmaxf(-d, 0.f);
        viol += (s.z == 1) ? pos : (s.z == 2) ? neg : (s.z == 3) ? (pos + neg) : 0.f;
        d = a.w - r.w; pos = fmaxf(d, 0.f); neg = fmaxf(-d, 0.f);
        viol += (s.w == 1) ? pos : (s.w == 2) ? neg : (s.w == 3) ? (pos + neg) : 0.f;
    }

    #pragma unroll
    for (int off = 32; off > 0; off >>= 1) {
        viol += __shfl_down(viol, off, 64);
    }
    int lane = threadIdx.x & 63;
    int wave = threadIdx.x >> 6;
    if (lane == 0) warp_sums[wave] = viol;
    __syncthreads();

    if (threadIdx.x == 0) {
        float s = warp_sums[0] + warp_sums[1] + warp_sums[2] + warp_sums[3];
        atomicAdd(out, s * inv_n);
    }
}

extern "C" void kernel_launch(void* const* d_in, const int* in_sizes, int n_in,
                              void* d_out, int out_size, void* d_ws, size_t ws_size,
                              hipStream_t stream) {
    const float* pred       = (const float*)d_in[0];
    const float* coeff      = (const float*)d_in[1];
    const float* rhs        = (const float*)d_in[2];
    const float* lb         = (const float*)d_in[3];
    const float* ub         = (const float*)d_in[4];
    const int*   constr_idx = (const int*)d_in[5];
    const int*   var_idx    = (const int*)d_in[6];
    const int*   sense      = (const int*)d_in[7];

    const int n_vars    = in_sizes[0];
    const int nnz       = in_sizes[1];
    const int n_constrs = in_sizes[2];

    _Float16* values_h = (_Float16*)d_ws;                       // n_vars fp16 (2 MB)
    float*    ax       = (float*)((char*)d_ws + (size_t)n_vars * sizeof(_Float16));
    float*    out      = (float*)d_out;

    const int BLK = 256;

    int n4v = n_vars / 4, n4c = n_constrs / 4;
    int n4max = (n4v > n4c) ? n4v : n4c;
    denorm_zero_kernel<<<(n4max + BLK - 1) / BLK, BLK, 0, stream>>>(
        (const vfloat4*)pred, (const vfloat4*)lb, (const vfloat4*)ub,
        (vhalf4*)values_h, (vfloat4*)ax, out, n4v, n4c);

    int nchunk = (nnz + 15) / 16;
    scatter_kernel<<<(nchunk + BLK - 1) / BLK, BLK, 0, stream>>>(
        (const vfloat4*)coeff, (const vint4*)constr_idx, (const vint4*)var_idx,
        values_h, ax, nnz);

    violation_kernel<<<(n4c + BLK - 1) / BLK, BLK, 0, stream>>>(
        (const vfloat4*)ax, (const vfloat4*)rhs, (const vint4*)sense,
        out, n4c, 1.0f / (float)n_constrs);
}

// Round 5
// 305.352 us; speedup vs baseline: 1.0485x; 1.0485x over previous
//
#include <hip/hip_runtime.h>
#include <hip/hip_fp16.h>

// Clang-native vector types (__builtin_nontemporal_load rejects HIP_vector_type).
typedef float    vfloat4 __attribute__((ext_vector_type(4)));
typedef int      vint4   __attribute__((ext_vector_type(4)));
typedef _Float16 vhalf4  __attribute__((ext_vector_type(4)));

// L1-bypassing 2-byte gather: agent-scope relaxed atomic load forces sc0
// (skip L1) on gfx950. Gathers never hit L1 anyway (random 2 MB table vs
// 32 KB L1); bypassing avoids the ~5.5 cyc/lane L1 miss-handling
// serialization that walls every variant at ~143 us.
__device__ __forceinline__ float gather_val(const unsigned short* tbl, int idx) {
    unsigned short raw = __hip_atomic_load(&tbl[idx], __ATOMIC_RELAXED,
                                           __HIP_MEMORY_SCOPE_AGENT);
    return (float)__builtin_bit_cast(_Float16, raw);
}

// Phase 1 (fused): values_h = fp16(pred*(ub-lb)+lb); zero ax; zero out.
__global__ void denorm_zero_kernel(const vfloat4* __restrict__ pred,
                                   const vfloat4* __restrict__ lb,
                                   const vfloat4* __restrict__ ub,
                                   vhalf4* __restrict__ values_h,
                                   vfloat4* __restrict__ ax,
                                   float* __restrict__ out,
                                   int n4v, int n4c) {
    int i = blockIdx.x * blockDim.x + threadIdx.x;
    if (i < n4v) {
        vfloat4 p = pred[i], l = lb[i], u = ub[i];
        vhalf4 h;
        h.x = (_Float16)fmaf(p.x, u.x - l.x, l.x);
        h.y = (_Float16)fmaf(p.y, u.y - l.y, l.y);
        h.z = (_Float16)fmaf(p.z, u.z - l.z, l.z);
        h.w = (_Float16)fmaf(p.w, u.w - l.w, l.w);
        values_h[i] = h;
    }
    if (i < n4c) {
        vfloat4 z = {0.f, 0.f, 0.f, 0.f};
        ax[i] = z;
    }
    if (i == 0) *out = 0.0f;
}

// Phase 2: thread-coarsened segmented sum (K=16), LDS row-window per block,
// one coalesced writeback (atomics only on the 2 boundary rows).
#define WIN 4096

__global__ void scatter_kernel(const vfloat4* __restrict__ coeff,
                               const vint4* __restrict__ cidx,
                               const vint4* __restrict__ vidx,
                               const unsigned short* __restrict__ values,
                               float* __restrict__ ax,
                               int nnz) {
    __shared__ float lwin[WIN];
    __shared__ int srow[2];
    const int K = 16;
    const int tib = threadIdx.x;

    long blockbase = (long)blockIdx.x * 256 * K;
    if (blockbase >= nnz) return;  // uniform per block

    for (int o = tib; o < WIN; o += 256) lwin[o] = 0.0f;
    if (tib == 0) {
        const int* ci = (const int*)cidx;
        srow[0] = ci[blockbase];
        long lastl = blockbase + 256L * K;
        if (lastl > nnz) lastl = nnz;
        srow[1] = ci[lastl - 1];
    }
    __syncthreads();
    const int rlo = srow[0];
    const int rhi = srow[1];

    long base = blockbase + (long)tib * K;
    if (base < nnz) {
        if (base + K <= nnz) {
            long b4 = base / 4;
            int cseg[16]; int vix[16]; float cf[16];
            #pragma unroll
            for (int j = 0; j < 4; j++) {
                vint4 c = __builtin_nontemporal_load(&cidx[b4 + j]);
                cseg[4*j+0] = c.x; cseg[4*j+1] = c.y; cseg[4*j+2] = c.z; cseg[4*j+3] = c.w;
            }
            #pragma unroll
            for (int j = 0; j < 4; j++) {
                vint4 v = __builtin_nontemporal_load(&vidx[b4 + j]);
                vix[4*j+0] = v.x; vix[4*j+1] = v.y; vix[4*j+2] = v.z; vix[4*j+3] = v.w;
            }
            float vals[16];
            #pragma unroll
            for (int k = 0; k < 16; k++) vals[k] = gather_val(values, vix[k]);
            #pragma unroll
            for (int j = 0; j < 4; j++) {
                vfloat4 f = __builtin_nontemporal_load(&coeff[b4 + j]);
                cf[4*j+0] = f.x; cf[4*j+1] = f.y; cf[4*j+2] = f.z; cf[4*j+3] = f.w;
            }

            int cur = cseg[0];
            float acc = cf[0] * vals[0];
            #pragma unroll
            for (int k = 1; k < 16; k++) {
                if (cseg[k] == cur) {
                    acc = fmaf(cf[k], vals[k], acc);
                } else {
                    unsigned off = (unsigned)(cur - rlo);
                    if (off < (unsigned)WIN) atomicAdd(&lwin[off], acc);
                    else atomicAdd(&ax[cur], acc);
                    cur = cseg[k];
                    acc = cf[k] * vals[k];
                }
            }
            unsigned off = (unsigned)(cur - rlo);
            if (off < (unsigned)WIN) atomicAdd(&lwin[off], acc);
            else atomicAdd(&ax[cur], acc);
        } else {
            // Tail chunk: scalar.
            const int* ci = (const int*)cidx;
            const int* vi = (const int*)vidx;
            const float* cf = (const float*)coeff;
            int cur = ci[base];
            float acc = cf[base] * gather_val(values, vi[base]);
            for (long k = base + 1; k < nnz; k++) {
                int s = ci[k];
                float p = cf[k] * gather_val(values, vi[k]);
                if (s == cur) acc += p;
                else {
                    unsigned off = (unsigned)(cur - rlo);
                    if (off < (unsigned)WIN) atomicAdd(&lwin[off], acc);
                    else atomicAdd(&ax[cur], acc);
                    cur = s; acc = p;
                }
            }
            unsigned off = (unsigned)(cur - rlo);
            if (off < (unsigned)WIN) atomicAdd(&lwin[off], acc);
            else atomicAdd(&ax[cur], acc);
        }
    }
    __syncthreads();

    // Coalesced writeback of the block's row range.
    int span = rhi - rlo + 1;
    int wl = span < WIN ? span : WIN;
    for (int o = tib; o < wl; o += 256) {
        int r = rlo + o;
        float v = lwin[o];
        if (r == rlo || r == rhi) atomicAdd(&ax[r], v);  // shared with neighbor blocks
        else ax[r] = v;                                   // exclusively owned
    }
}

// Phase 3: violations by sense (x4 vectorized), block reduce, one atomic.
__global__ void violation_kernel(const vfloat4* __restrict__ ax,
                                 const vfloat4* __restrict__ rhs,
                                 const vint4* __restrict__ sense,
                                 float* __restrict__ out,
                                 int n4, float inv_n) {
    __shared__ float warp_sums[4];
    int i = blockIdx.x * blockDim.x + threadIdx.x;

    float viol = 0.0f;
    if (i < n4) {
        vfloat4 a = ax[i], r = rhs[i];
        vint4 s = sense[i];
        float d, pos, neg;
        d = a.x - r.x; pos = fmaxf(d, 0.f); neg = fmaxf(-d, 0.f);
        viol += (s.x == 1) ? pos : (s.x == 2) ? neg : (s.x == 3) ? (pos + neg) : 0.f;
        d = a.y - r.y; pos = fmaxf(d, 0.f); neg = fmaxf(-d, 0.f);
        viol += (s.y == 1) ? pos : (s.y == 2) ? neg : (s.y == 3) ? (pos + neg) : 0.f;
        d = a.z - r.z; pos = fmaxf(d, 0.f); neg = fmaxf(-d, 0.f);
        viol += (s.z == 1) ? pos : (s.z == 2) ? neg : (s.z == 3) ? (pos + neg) : 0.f;
        d = a.w - r.w; pos = fmaxf(d, 0.f); neg = fmaxf(-d, 0.f);
        viol += (s.w == 1) ? pos : (s.w == 2) ? neg : (s.w == 3) ? (pos + neg) : 0.f;
    }

    #pragma unroll
    for (int off = 32; off > 0; off >>= 1) {
        viol += __shfl_down(viol, off, 64);
    }
    int lane = threadIdx.x & 63;
    int wave = threadIdx.x >> 6;
    if (lane == 0) warp_sums[wave] = viol;
    __syncthreads();

    if (threadIdx.x == 0) {
        float s = warp_sums[0] + warp_sums[1] + warp_sums[2] + warp_sums[3];
        atomicAdd(out, s * inv_n);
    }
}

extern "C" void kernel_launch(void* const* d_in, const int* in_sizes, int n_in,
                              void* d_out, int out_size, void* d_ws, size_t ws_size,
                              hipStream_t stream) {
    const float* pred       = (const float*)d_in[0];
    const float* coeff      = (const float*)d_in[1];
    const float* rhs        = (const float*)d_in[2];
    const float* lb         = (const float*)d_in[3];
    const float* ub         = (const float*)d_in[4];
    const int*   constr_idx = (const int*)d_in[5];
    const int*   var_idx    = (const int*)d_in[6];
    const int*   sense      = (const int*)d_in[7];

    const int n_vars    = in_sizes[0];
    const int nnz       = in_sizes[1];
    const int n_constrs = in_sizes[2];

    unsigned short* values_h = (unsigned short*)d_ws;           // n_vars fp16 (2 MB)
    float*          ax       = (float*)((char*)d_ws + (size_t)n_vars * sizeof(unsigned short));
    float*          out      = (float*)d_out;

    const int BLK = 256;

    int n4v = n_vars / 4, n4c = n_constrs / 4;
    int n4max = (n4v > n4c) ? n4v : n4c;
    denorm_zero_kernel<<<(n4max + BLK - 1) / BLK, BLK, 0, stream>>>(
        (const vfloat4*)pred, (const vfloat4*)lb, (const vfloat4*)ub,
        (vhalf4*)values_h, (vfloat4*)ax, out, n4v, n4c);

    int nchunk = (nnz + 15) / 16;
    scatter_kernel<<<(nchunk + BLK - 1) / BLK, BLK, 0, stream>>>(
        (const vfloat4*)coeff, (const vint4*)constr_idx, (const vint4*)var_idx,
        values_h, ax, nnz);

    violation_kernel<<<(n4c + BLK - 1) / BLK, BLK, 0, stream>>>(
        (const vfloat4*)ax, (const vfloat4*)rhs, (const vint4*)sense,
        out, n4c, 1.0f / (float)n_constrs);
}

// Round 6
// 305.180 us; speedup vs baseline: 1.0491x; 1.0006x over previous
//
#include <hip/hip_runtime.h>
#include <hip/hip_fp16.h>

// Clang-native vector types (__builtin_nontemporal_load rejects HIP_vector_type).
typedef float    vfloat4 __attribute__((ext_vector_type(4)));
typedef int      vint4   __attribute__((ext_vector_type(4)));
typedef _Float16 vhalf4  __attribute__((ext_vector_type(4)));

// Bypass gather: agent-scope relaxed atomic load -> sc0, skips L1, lands in
// the L2-request path.
__device__ __forceinline__ float gather_bypass(const unsigned short* tbl, int idx) {
    unsigned short raw = __hip_atomic_load(&tbl[idx], __ATOMIC_RELAXED,
                                           __HIP_MEMORY_SCOPE_AGENT);
    return (float)__builtin_bit_cast(_Float16, raw);
}
// Normal cached gather: goes through L1/TCP MSHR path.
__device__ __forceinline__ float gather_l1(const unsigned short* tbl, int idx) {
    return (float)__builtin_bit_cast(_Float16, tbl[idx]);
}

// Phase 1 (fused): values_h = fp16(pred*(ub-lb)+lb); zero ax; zero out.
__global__ void denorm_zero_kernel(const vfloat4* __restrict__ pred,
                                   const vfloat4* __restrict__ lb,
                                   const vfloat4* __restrict__ ub,
                                   vhalf4* __restrict__ values_h,
                                   vfloat4* __restrict__ ax,
                                   float* __restrict__ out,
                                   int n4v, int n4c) {
    int i = blockIdx.x * blockDim.x + threadIdx.x;
    if (i < n4v) {
        vfloat4 p = pred[i], l = lb[i], u = ub[i];
        vhalf4 h;
        h.x = (_Float16)fmaf(p.x, u.x - l.x, l.x);
        h.y = (_Float16)fmaf(p.y, u.y - l.y, l.y);
        h.z = (_Float16)fmaf(p.z, u.z - l.z, l.z);
        h.w = (_Float16)fmaf(p.w, u.w - l.w, l.w);
        values_h[i] = h;
    }
    if (i < n4c) {
        vfloat4 z = {0.f, 0.f, 0.f, 0.f};
        ax[i] = z;
    }
    if (i == 0) *out = 0.0f;
}

// Phase 2: thread-coarsened segmented sum (K=16), LDS row-window per block,
// one coalesced writeback (atomics only on the 2 boundary rows).
// Gathers split 50/50 between the L1 path and the sc0-bypass path to use
// both pending-request queues (experiment: MSHR-cap vs TA-rate wall).
#define WIN 4096

__global__ void scatter_kernel(const vfloat4* __restrict__ coeff,
                               const vint4* __restrict__ cidx,
                               const vint4* __restrict__ vidx,
                               const unsigned short* __restrict__ values,
                               float* __restrict__ ax,
                               int nnz) {
    __shared__ float lwin[WIN];
    __shared__ int srow[2];
    const int K = 16;
    const int tib = threadIdx.x;

    long blockbase = (long)blockIdx.x * 256 * K;
    if (blockbase >= nnz) return;  // uniform per block

    for (int o = tib; o < WIN; o += 256) lwin[o] = 0.0f;
    if (tib == 0) {
        const int* ci = (const int*)cidx;
        srow[0] = ci[blockbase];
        long lastl = blockbase + 256L * K;
        if (lastl > nnz) lastl = nnz;
        srow[1] = ci[lastl - 1];
    }
    __syncthreads();
    const int rlo = srow[0];
    const int rhi = srow[1];

    long base = blockbase + (long)tib * K;
    if (base < nnz) {
        if (base + K <= nnz) {
            long b4 = base / 4;
            int cseg[16]; int vix[16]; float cf[16];
            #pragma unroll
            for (int j = 0; j < 4; j++) {
                vint4 c = __builtin_nontemporal_load(&cidx[b4 + j]);
                cseg[4*j+0] = c.x; cseg[4*j+1] = c.y; cseg[4*j+2] = c.z; cseg[4*j+3] = c.w;
            }
            #pragma unroll
            for (int j = 0; j < 4; j++) {
                vint4 v = __builtin_nontemporal_load(&vidx[b4 + j]);
                vix[4*j+0] = v.x; vix[4*j+1] = v.y; vix[4*j+2] = v.z; vix[4*j+3] = v.w;
            }
            float vals[16];
            #pragma unroll
            for (int k = 0; k < 16; k += 2) {
                vals[k]     = gather_l1(values, vix[k]);       // L1/MSHR path
                vals[k + 1] = gather_bypass(values, vix[k+1]); // sc0/L2 path
            }
            #pragma unroll
            for (int j = 0; j < 4; j++) {
                vfloat4 f = __builtin_nontemporal_load(&coeff[b4 + j]);
                cf[4*j+0] = f.x; cf[4*j+1] = f.y; cf[4*j+2] = f.z; cf[4*j+3] = f.w;
            }

            int cur = cseg[0];
            float acc = cf[0] * vals[0];
            #pragma unroll
            for (int k = 1; k < 16; k++) {
                if (cseg[k] == cur) {
                    acc = fmaf(cf[k], vals[k], acc);
                } else {
                    unsigned off = (unsigned)(cur - rlo);
                    if (off < (unsigned)WIN) atomicAdd(&lwin[off], acc);
                    else atomicAdd(&ax[cur], acc);
                    cur = cseg[k];
                    acc = cf[k] * vals[k];
                }
            }
            unsigned off = (unsigned)(cur - rlo);
            if (off < (unsigned)WIN) atomicAdd(&lwin[off], acc);
            else atomicAdd(&ax[cur], acc);
        } else {
            // Tail chunk: scalar.
            const int* ci = (const int*)cidx;
            const int* vi = (const int*)vidx;
            const float* cf = (const float*)coeff;
            int cur = ci[base];
            float acc = cf[base] * gather_bypass(values, vi[base]);
            for (long k = base + 1; k < nnz; k++) {
                int s = ci[k];
                float p = cf[k] * gather_bypass(values, vi[k]);
                if (s == cur) acc += p;
                else {
                    unsigned off = (unsigned)(cur - rlo);
                    if (off < (unsigned)WIN) atomicAdd(&lwin[off], acc);
                    else atomicAdd(&ax[cur], acc);
                    cur = s; acc = p;
                }
            }
            unsigned off = (unsigned)(cur - rlo);
            if (off < (unsigned)WIN) atomicAdd(&lwin[off], acc);
            else atomicAdd(&ax[cur], acc);
        }
    }
    __syncthreads();

    // Coalesced writeback of the block's row range.
    int span = rhi - rlo + 1;
    int wl = span < WIN ? span : WIN;
    for (int o = tib; o < wl; o += 256) {
        int r = rlo + o;
        float v = lwin[o];
        if (r == rlo || r == rhi) atomicAdd(&ax[r], v);  // shared with neighbor blocks
        else ax[r] = v;                                   // exclusively owned
    }
}

// Phase 3: violations by sense (x4 vectorized), block reduce, one atomic.
__global__ void violation_kernel(const vfloat4* __restrict__ ax,
                                 const vfloat4* __restrict__ rhs,
                                 const vint4* __restrict__ sense,
                                 float* __restrict__ out,
                                 int n4, float inv_n) {
    __shared__ float warp_sums[4];
    int i = blockIdx.x * blockDim.x + threadIdx.x;

    float viol = 0.0f;
    if (i < n4) {
        vfloat4 a = ax[i], r = rhs[i];
        vint4 s = sense[i];
        float d, pos, neg;
        d = a.x - r.x; pos = fmaxf(d, 0.f); neg = fmaxf(-d, 0.f);
        viol += (s.x == 1) ? pos : (s.x == 2) ? neg : (s.x == 3) ? (pos + neg) : 0.f;
        d = a.y - r.y; pos = fmaxf(d, 0.f); neg = fmaxf(-d, 0.f);
        viol += (s.y == 1) ? pos : (s.y == 2) ? neg : (s.y == 3) ? (pos + neg) : 0.f;
        d = a.z - r.z; pos = fmaxf(d, 0.f); neg = fmaxf(-d, 0.f);
        viol += (s.z == 1) ? pos : (s.z == 2) ? neg : (s.z == 3) ? (pos + neg) : 0.f;
        d = a.w - r.w; pos = fmaxf(d, 0.f); neg = fmaxf(-d, 0.f);
        viol += (s.w == 1) ? pos : (s.w == 2) ? neg : (s.w == 3) ? (pos + neg) : 0.f;
    }

    #pragma unroll
    for (int off = 32; off > 0; off >>= 1) {
        viol += __shfl_down(viol, off, 64);
    }
    int lane = threadIdx.x & 63;
    int wave = threadIdx.x >> 6;
    if (lane == 0) warp_sums[wave] = viol;
    __syncthreads();

    if (threadIdx.x == 0) {
        float s = warp_sums[0] + warp_sums[1] + warp_sums[2] + warp_sums[3];
        atomicAdd(out, s * inv_n);
    }
}

extern "C" void kernel_launch(void* const* d_in, const int* in_sizes, int n_in,
                              void* d_out, int out_size, void* d_ws, size_t ws_size,
                              hipStream_t stream) {
    const float* pred       = (const float*)d_in[0];
    const float* coeff      = (const float*)d_in[1];
    const float* rhs        = (const float*)d_in[2];
    const float* lb         = (const float*)d_in[3];
    const float* ub         = (const float*)d_in[4];
    const int*   constr_idx = (const int*)d_in[5];
    const int*   var_idx    = (const int*)d_in[6];
    const int*   sense      = (const int*)d_in[7];

    const int n_vars    = in_sizes[0];
    const int nnz       = in_sizes[1];
    const int n_constrs = in_sizes[2];

    unsigned short* values_h = (unsigned short*)d_ws;           // n_vars fp16 (2 MB)
    float*          ax       = (float*)((char*)d_ws + (size_t)n_vars * sizeof(unsigned short));
    float*          out      = (float*)d_out;

    const int BLK = 256;

    int n4v = n_vars / 4, n4c = n_constrs / 4;
    int n4max = (n4v > n4c) ? n4v : n4c;
    denorm_zero_kernel<<<(n4max + BLK - 1) / BLK, BLK, 0, stream>>>(
        (const vfloat4*)pred, (const vfloat4*)lb, (const vfloat4*)ub,
        (vhalf4*)values_h, (vfloat4*)ax, out, n4v, n4c);

    int nchunk = (nnz + 15) / 16;
    scatter_kernel<<<(nchunk + BLK - 1) / BLK, BLK, 0, stream>>>(
        (const vfloat4*)coeff, (const vint4*)constr_idx, (const vint4*)var_idx,
        values_h, ax, nnz);

    violation_kernel<<<(n4c + BLK - 1) / BLK, BLK, 0, stream>>>(
        (const vfloat4*)ax, (const vfloat4*)rhs, (const vint4*)sense,
        out, n4c, 1.0f / (float)n_constrs);
}